// Round 3
// baseline (293.166 us; speedup 1.0000x reference)
//
#include <hip/hip_runtime.h>
#include <hip/hip_bf16.h>

// HLiuAttn: out = softmax((x W_qkv^T).q @ .k^T / sqrt(D)) @ .v
// B=4, N=2048, D=1024. fp32 in/out; bf16 MFMA internally (m97-structure GEMM).

typedef __bf16 bf16x8 __attribute__((ext_vector_type(8)));
typedef float f32x4 __attribute__((ext_vector_type(4)));

__device__ __forceinline__ void gload_lds16(const __hip_bfloat16* g, __hip_bfloat16* l) {
  __builtin_amdgcn_global_load_lds(
      (const __attribute__((address_space(1))) void*)g,
      (__attribute__((address_space(3))) void*)l, 16, 0, 0);
}

__device__ __forceinline__ void store_out(float* p, float v) { *p = v; }
__device__ __forceinline__ void store_out(__hip_bfloat16* p, float v) { *p = __float2bfloat16(v); }

// ---------------- cast fp32 -> bf16 (vectorized float4 -> 4x bf16) ----------------
__global__ __launch_bounds__(256)
void cast_f32_bf16(const float* __restrict__ in, __hip_bfloat16* __restrict__ out, int n4) {
  for (int i = blockIdx.x * blockDim.x + threadIdx.x; i < n4; i += gridDim.x * blockDim.x) {
    float4 v = ((const float4*)in)[i];
    __hip_bfloat16 b0 = __float2bfloat16(v.x), b1 = __float2bfloat16(v.y),
                   b2 = __float2bfloat16(v.z), b3 = __float2bfloat16(v.w);
    ushort4 o;
    o.x = *(unsigned short*)&b0; o.y = *(unsigned short*)&b1;
    o.z = *(unsigned short*)&b2; o.w = *(unsigned short*)&b3;
    ((ushort4*)out)[i] = o;
  }
}

// ---------------- m97-style 128x128 GEMM, A [M x K] row-major, B^T [N x K] row-major ----------------
// C[m,n] = sum_k A[m,k]*B^T[n,k];  OutT in {float, bf16}. Batched via blockIdx.z.
template <typename OutT>
__global__ __launch_bounds__(256)
void gemm_bt(const __hip_bfloat16* __restrict__ A, int lda, long sA,
             const __hip_bfloat16* __restrict__ B, int ldb, long sB,
             OutT* __restrict__ C, int ldc, long sC,
             int K, float cscale) {
  constexpr int BK = 64;
  __shared__ __hip_bfloat16 As[128 * BK];  // [row][k], linear (global_load_lds needs linear dest)
  __shared__ __hip_bfloat16 Bs[128 * BK];  // [col][k]
  const int tid = threadIdx.x, lane = tid & 63, wid = tid >> 6;
  const int wr = wid >> 1, wc = wid & 1;   // wave -> 64x64 quadrant
  A += (long)blockIdx.z * sA; B += (long)blockIdx.z * sB; C += (long)blockIdx.z * sC;
  const long bm = (long)blockIdx.x * 128, bn = (long)blockIdx.y * 128;
  const int lrow = lane & 15, lk8 = lane >> 4;
  f32x4 acc[4][4] = {};

  for (int k0 = 0; k0 < K; k0 += BK) {
    // stage A,B tiles: 4 issues each, 16B/lane, LDS dest = wave-uniform base + lane*16
#pragma unroll
    for (int i = 0; i < 4; ++i) {
      int p = i * 256 + tid;
      int row = p >> 3, g = p & 7;
      gload_lds16(A + (bm + row) * (long)lda + k0 + g * 8, &As[(i * 256 + (wid << 6)) * 8]);
    }
#pragma unroll
    for (int i = 0; i < 4; ++i) {
      int p = i * 256 + tid;
      int row = p >> 3, g = p & 7;
      gload_lds16(B + (bn + row) * (long)ldb + k0 + g * 8, &Bs[(i * 256 + (wid << 6)) * 8]);
    }
    __syncthreads();  // compiler drains vmcnt before s_barrier
#pragma unroll
    for (int kk = 0; kk < 2; ++kk) {
      bf16x8 af[4], bfr[4];
#pragma unroll
      for (int m = 0; m < 4; ++m)
        af[m] = *(const bf16x8*)&As[(wr * 64 + m * 16 + lrow) * BK + kk * 32 + lk8 * 8];
#pragma unroll
      for (int n = 0; n < 4; ++n)
        bfr[n] = *(const bf16x8*)&Bs[(wc * 64 + n * 16 + lrow) * BK + kk * 32 + lk8 * 8];
#pragma unroll
      for (int m = 0; m < 4; ++m)
#pragma unroll
        for (int n = 0; n < 4; ++n)
          acc[m][n] = __builtin_amdgcn_mfma_f32_16x16x32_bf16(af[m], bfr[n], acc[m][n], 0, 0, 0);
    }
    __syncthreads();
  }

  // epilogue: C/D layout col=lane&15, row=(lane>>4)*4+j  [m89-verified]
  const int r0 = (lane >> 4) * 4;
#pragma unroll
  for (int m = 0; m < 4; ++m)
#pragma unroll
    for (int n = 0; n < 4; ++n) {
      long col = bn + wc * 64 + n * 16 + lrow;
      long row = bm + wr * 64 + m * 16 + r0;
#pragma unroll
      for (int j = 0; j < 4; ++j)
        store_out(&C[(row + j) * (long)ldc + col], acc[m][n][j] * cscale);
    }
}

// ---------------- V transpose: Vt[b][d][m] = qkv[b*2048+m][2048+d] ----------------
__global__ __launch_bounds__(256)
void transpose_v(const __hip_bfloat16* __restrict__ qkv, __hip_bfloat16* __restrict__ Vt) {
  __shared__ __hip_bfloat16 tile[32][33];
  const int b = blockIdx.z;
  const __hip_bfloat16* V = qkv + (size_t)b * 2048 * 3072 + 2048;
  __hip_bfloat16* vt = Vt + (size_t)b * 1024 * 2048;
  const int tx = threadIdx.x & 31, ty = threadIdx.x >> 5;  // 32 x 8
  const int m0 = blockIdx.x * 32, d0 = blockIdx.y * 32;
#pragma unroll
  for (int i = 0; i < 32; i += 8)
    tile[ty + i][tx] = V[(size_t)(m0 + ty + i) * 3072 + d0 + tx];
  __syncthreads();
#pragma unroll
  for (int i = 0; i < 32; i += 8)
    vt[(size_t)(d0 + ty + i) * 2048 + m0 + tx] = tile[tx][ty + i];
}

// ---------------- row softmax over 2048 fp32, writes bf16 P in-place (stride 4096 bf16/row) ----------------
__global__ __launch_bounds__(256)
void softmax_rows(float* __restrict__ S) {
  float* row = S + (size_t)blockIdx.x * 2048;
  const int t = threadIdx.x, lane = t & 63, wid = t >> 6;
  float4 v0 = ((const float4*)row)[t];
  float4 v1 = ((const float4*)row)[256 + t];
  float vals[8] = {v0.x, v0.y, v0.z, v0.w, v1.x, v1.y, v1.z, v1.w};
  float m = vals[0];
#pragma unroll
  for (int i = 1; i < 8; ++i) m = fmaxf(m, vals[i]);
#pragma unroll
  for (int o = 32; o; o >>= 1) m = fmaxf(m, __shfl_xor(m, o));
  __shared__ float red[4];
  if (lane == 0) red[wid] = m;
  __syncthreads();
  m = fmaxf(fmaxf(red[0], red[1]), fmaxf(red[2], red[3]));
  __syncthreads();
  float p[8], s = 0.f;
#pragma unroll
  for (int i = 0; i < 8; ++i) { p[i] = __expf(vals[i] - m); s += p[i]; }
#pragma unroll
  for (int o = 32; o; o >>= 1) s += __shfl_xor(s, o);
  if (lane == 0) red[wid] = s;
  __syncthreads();
  s = red[0] + red[1] + red[2] + red[3];
  const float inv = 1.0f / s;
  __hip_bfloat16 b[8];
#pragma unroll
  for (int i = 0; i < 8; ++i) b[i] = __float2bfloat16(p[i] * inv);
  ushort4 o0, o1;
  o0.x = *(unsigned short*)&b[0]; o0.y = *(unsigned short*)&b[1];
  o0.z = *(unsigned short*)&b[2]; o0.w = *(unsigned short*)&b[3];
  o1.x = *(unsigned short*)&b[4]; o1.y = *(unsigned short*)&b[5];
  o1.z = *(unsigned short*)&b[6]; o1.w = *(unsigned short*)&b[7];
  unsigned short* prow = (unsigned short*)row;
  ((ushort4*)prow)[t] = o0;        // bf16 elems 4t..4t+3 (all reads done before 1st barrier)
  ((ushort4*)prow)[256 + t] = o1;  // bf16 elems 1024+4t..
}

extern "C" void kernel_launch(void* const* d_in, const int* in_sizes, int n_in,
                              void* d_out, int out_size, void* d_ws, size_t ws_size,
                              hipStream_t stream) {
  const float* x = (const float*)d_in[0];   // [4,2048,1024]
  const float* w = (const float*)d_in[1];   // [3072,1024]
  float* out = (float*)d_out;               // [4,2048,1024] fp32
  char* ws = (char*)d_ws;

  // ws layout (128 MiB total):
  //   [0, 67MB)        S fp32 (4 x 2048 x 2048); early-reused for cast buffers
  //   [67MB, 117.4MB)  qkv bf16 [8192 x 3072]
  //   [117.4MB, 128MB) Vt bf16 [4][1024][2048]
  __hip_bfloat16* xb  = (__hip_bfloat16*)ws;                          // 8M elems (16.8 MB)
  __hip_bfloat16* wb  = (__hip_bfloat16*)(ws + 16777216);             // 3M elems (6.3 MB)
  float*          S   = (float*)ws;                                   // 67.1 MB (overwrites xb/wb later)
  __hip_bfloat16* qkv = (__hip_bfloat16*)(ws + 67108864);             // 50.3 MB
  __hip_bfloat16* Vt  = (__hip_bfloat16*)(ws + 117440512);            // 16.8 MB

  // 1) casts
  cast_f32_bf16<<<1024, 256, 0, stream>>>(x, xb, (4 * 2048 * 1024) / 4);
  cast_f32_bf16<<<512, 256, 0, stream>>>(w, wb, (3072 * 1024) / 4);

  // 2) qkv = x @ w^T   [8192 x 3072], K=1024
  gemm_bt<__hip_bfloat16><<<dim3(64, 24, 1), 256, 0, stream>>>(
      xb, 1024, 0L, wb, 1024, 0L, qkv, 3072, 0L, 1024, 1.0f);

  // 3) Vt[b][d][m]
  transpose_v<<<dim3(64, 32, 4), 256, 0, stream>>>(qkv, Vt);

  // 4) S_b = (Q_b K_b^T) / 32   [2048 x 2048] x4, K=1024
  gemm_bt<float><<<dim3(16, 16, 4), 256, 0, stream>>>(
      qkv, 3072, (long)2048 * 3072, qkv + 1024, 3072, (long)2048 * 3072,
      S, 2048, (long)2048 * 2048, 1024, 0.03125f);

  // 5) row softmax, P bf16 in-place (row stride 4096 bf16)
  softmax_rows<<<8192, 256, 0, stream>>>(S);

  // 6) out_b = P_b @ V_b   [2048 x 1024] x4, K=2048, B = Vt (B^T layout)
  gemm_bt<float><<<dim3(16, 8, 4), 256, 0, stream>>>(
      (const __hip_bfloat16*)S, 4096, (long)2048 * 4096,
      Vt, 2048, (long)1024 * 2048,
      out, 1024, (long)2048 * 1024, 2048, 1.0f);
}

// Round 4
// 267.944 us; speedup vs baseline: 1.0941x; 1.0941x over previous
//
#include <hip/hip_runtime.h>
#include <hip/hip_bf16.h>

// HLiuAttn: out = softmax((x W_qkv^T).q @ .k^T / 32) @ .v
// B=4, N=2048, D=1024. fp32 in/out; bf16 MFMA internally.
// R4: GEMMs ported to 256x256 8-phase template (T2 st_16x32 swizzle + T3/T4
// counted vmcnt + T5 setprio). 512 thr, 8 waves 2x4, BK=64, 128 KiB LDS dbuf.

typedef __bf16 bf16x8 __attribute__((ext_vector_type(8)));
typedef float f32x4 __attribute__((ext_vector_type(4)));

__device__ __forceinline__ void store_out(float* p, float v) { *p = v; }
__device__ __forceinline__ void store_out(__hip_bfloat16* p, float v) { *p = __float2bfloat16(v); }

// ---------------- cast fp32 -> bf16 ----------------
__global__ __launch_bounds__(256)
void cast_f32_bf16(const float* __restrict__ in, __hip_bfloat16* __restrict__ out, int n4) {
  for (int i = blockIdx.x * blockDim.x + threadIdx.x; i < n4; i += gridDim.x * blockDim.x) {
    float4 v = ((const float4*)in)[i];
    __hip_bfloat16 b0 = __float2bfloat16(v.x), b1 = __float2bfloat16(v.y),
                   b2 = __float2bfloat16(v.z), b3 = __float2bfloat16(v.w);
    ushort4 o;
    o.x = *(unsigned short*)&b0; o.y = *(unsigned short*)&b1;
    o.z = *(unsigned short*)&b2; o.w = *(unsigned short*)&b3;
    ((ushort4*)out)[i] = o;
  }
}

// ---------------- 256x256 8-phase GEMM ----------------
// C[m,n] = sum_k A[m,k] * B^T[n,k].  A [M x K] rm, B^T [N x K] rm.
//
// LDS per buffer: A 256x64 bf16 (32KB) + B 256x64 (32KB); 2 buffers = 128KB.
// Layout: subtiled [row/16][k/32][16][32] (1024B subtiles); within subtile
// byte = (row&15)*64 + ((k&31)*2 ^ ((row&8)?32:0))   <- st_16x32 XOR swizzle.
// global_load_lds writes LINEAR (wave-uniform base + lane*16); the swizzle is
// realized by inverse-permuting the per-lane GLOBAL source column (rule 21).
//
// Staging ledger (per K-tile t, issued for tile t+1 into buf[c^1], 2 loads/phase):
//   ph0: A rows 0-63, 128-191 (l0 pair)    idx 0,1
//   ph1: B rows 0-63, 64-127   (HB0)       idx 2,3
//   ph2: B rows 128-191, 192-255 (HB1)     idx 4,5
//   ph3: A rows 64-127, 192-255 (l1 pair)  idx 6,7
// Reads: ph0 of tile t needs t's idx 0-5 -> guarded by t-1 ph3's vmcnt(2)
//        ph2/ph3 need t's idx 6,7        -> guarded by t ph1's vmcnt(4)
//        (outstanding at t ph1 wait: idx6,7(t) + 2(t+1 ph0) + 2(t+1 ph1) = 6 -> wait to 4)
// vmcnt waits sit BEFORE a barrier; dependent ds_reads AFTER it (vmcnt is per-wave;
// barrier broadcasts the guarantee). Never vmcnt(0) mid-loop.

#define PHASE(P, CB, PF, K0N)                                                          \
  {                                                                                    \
    bf16x8 a00 = frag(CB, 0, wm * 128 + P * 32 +  0, 0);                               \
    bf16x8 a01 = frag(CB, 0, wm * 128 + P * 32 +  0, 1);                               \
    bf16x8 a10 = frag(CB, 0, wm * 128 + P * 32 + 16, 0);                               \
    bf16x8 a11 = frag(CB, 0, wm * 128 + P * 32 + 16, 1);                               \
    if (P == 0) {                                                                      \
      _Pragma("unroll") for (int j = 0; j < 4; ++j) {                                  \
        bfr[j][0] = frag(CB, 1, wn * 64 + j * 16, 0);                                  \
        bfr[j][1] = frag(CB, 1, wn * 64 + j * 16, 1);                                  \
      }                                                                                \
    }                                                                                  \
    if (PF) {                                                                          \
      if (P == 0) { stage(CB ^ 1, 0,   0, K0N); stage(CB ^ 1, 0, 128, K0N); }          \
      if (P == 1) { stage(CB ^ 1, 1,   0, K0N); stage(CB ^ 1, 1,  64, K0N); }          \
      if (P == 2) { stage(CB ^ 1, 1, 128, K0N); stage(CB ^ 1, 1, 192, K0N); }          \
      if (P == 3) { stage(CB ^ 1, 0,  64, K0N); stage(CB ^ 1, 0, 192, K0N); }          \
    }                                                                                  \
    if (P == 0) asm volatile("s_waitcnt lgkmcnt(8)" ::: "memory");                     \
    if (P == 1) {                                                                      \
      if (PF) asm volatile("s_waitcnt vmcnt(4)" ::: "memory");                         \
      else    asm volatile("s_waitcnt vmcnt(0)" ::: "memory");                         \
    }                                                                                  \
    if (P == 3) { if (PF) asm volatile("s_waitcnt vmcnt(2)" ::: "memory"); }           \
    __builtin_amdgcn_s_barrier();                                                      \
    asm volatile("s_waitcnt lgkmcnt(0)" ::: "memory");                                 \
    __builtin_amdgcn_sched_barrier(0);                                                 \
    __builtin_amdgcn_s_setprio(1);                                                     \
    _Pragma("unroll") for (int j = 0; j < 4; ++j) {                                    \
      acc[P * 2 + 0][j] = __builtin_amdgcn_mfma_f32_16x16x32_bf16(a00, bfr[j][0], acc[P * 2 + 0][j], 0, 0, 0); \
      acc[P * 2 + 0][j] = __builtin_amdgcn_mfma_f32_16x16x32_bf16(a01, bfr[j][1], acc[P * 2 + 0][j], 0, 0, 0); \
      acc[P * 2 + 1][j] = __builtin_amdgcn_mfma_f32_16x16x32_bf16(a10, bfr[j][0], acc[P * 2 + 1][j], 0, 0, 0); \
      acc[P * 2 + 1][j] = __builtin_amdgcn_mfma_f32_16x16x32_bf16(a11, bfr[j][1], acc[P * 2 + 1][j], 0, 0, 0); \
    }                                                                                  \
    __builtin_amdgcn_s_setprio(0);                                                     \
    __builtin_amdgcn_s_barrier();                                                      \
  }

template <typename OutT>
__global__ __launch_bounds__(512, 2)
void gemm256(const __hip_bfloat16* __restrict__ A, int lda, long sA,
             const __hip_bfloat16* __restrict__ B, int ldb, long sB,
             OutT* __restrict__ C, int ldc, long sC,
             int K, float cscale) {
  extern __shared__ char smem[];  // 131072 B
  const int tid = threadIdx.x, lane = tid & 63, wid = tid >> 6;
  const int wm = wid >> 2, wn = wid & 3;  // wave -> 128x64 output panel
  A += (long)blockIdx.z * sA; B += (long)blockIdx.z * sB; C += (long)blockIdx.z * sC;
  const long bm = (long)blockIdx.x * 256, bn = (long)blockIdx.y * 256;
  // read-side: lane offset within 1024B subtile (swizzled; 4-way residual conflict)
  const int laneOff = (lane & 15) * 64 + (((lane >> 4) * 16) ^ ((lane & 8) ? 32 : 0));
  // stage-side: each wave fills one 1024B subtile per gload; lane writes lane*16
  const int sRowA = (wid >> 1) * 16 + (lane >> 2);                 // row within 64-row chunk
  const int sKs   = wid & 1;                                       // k-subtile staged by this wave
  const int sCol  = ((lane & 3) * 8) ^ ((lane & 32) ? 16 : 0);     // inverse-swizzled k elem
  const int nt = K >> 6;

  auto stage = [&](int cbuf, int reg /*0=A,1=B*/, int row0, int k0) {
    const __hip_bfloat16* g =
        reg ? (B + (bn + row0 + sRowA) * (long)ldb + k0 + sKs * 32 + sCol)
            : (A + (bm + row0 + sRowA) * (long)lda + k0 + sKs * 32 + sCol);
    char* dst = smem + cbuf * 65536 + reg * 32768 + ((row0 >> 4) * 2 + wid) * 1024;
    __builtin_amdgcn_global_load_lds((const __attribute__((address_space(1))) void*)g,
                                     (__attribute__((address_space(3))) void*)dst, 16, 0, 0);
  };
  auto frag = [&](int cbuf, int reg, int R, int ks) -> bf16x8 {
    return *(const bf16x8*)(smem + cbuf * 65536 + reg * 32768 +
                            ((R >> 4) * 2 + ks) * 1024 + laneOff);
  };

  f32x4 acc[8][4] = {};
  bf16x8 bfr[4][2];

  // prologue: tile 0 in canonical order, then guarantee idx 0-5 landed
  stage(0, 0,   0, 0); stage(0, 0, 128, 0);
  stage(0, 1,   0, 0); stage(0, 1,  64, 0);
  stage(0, 1, 128, 0); stage(0, 1, 192, 0);
  stage(0, 0,  64, 0); stage(0, 0, 192, 0);
  asm volatile("s_waitcnt vmcnt(2)" ::: "memory");
  __builtin_amdgcn_s_barrier();

  for (int t = 0; t < nt; t += 2) {
    {
      const int k0n = (t + 1) << 6;  // t+1 < nt always (nt even)
      PHASE(0, 0, true, k0n) PHASE(1, 0, true, k0n)
      PHASE(2, 0, true, k0n) PHASE(3, 0, true, k0n)
    }
    {
      const bool pf = (t + 2) < nt;
      const int k0n = (t + 2) << 6;
      PHASE(0, 1, pf, k0n) PHASE(1, 1, pf, k0n)
      PHASE(2, 1, pf, k0n) PHASE(3, 1, pf, k0n)
    }
  }

  // epilogue: C/D layout col=lane&15, row=(lane>>4)*4+jj [m89-verified]
  const int r0 = (lane >> 4) * 4, cn = lane & 15;
#pragma unroll
  for (int rf = 0; rf < 8; ++rf)
#pragma unroll
    for (int j = 0; j < 4; ++j) {
      long row = bm + wm * 128 + rf * 16 + r0;
      long col = bn + wn * 64 + j * 16 + cn;
#pragma unroll
      for (int jj = 0; jj < 4; ++jj)
        store_out(&C[(row + jj) * (long)ldc + col], acc[rf][j][jj] * cscale);
    }
}

// ---------------- V transpose: Vt[b][d][m] = qkv[b*2048+m][2048+d] ----------------
__global__ __launch_bounds__(256)
void transpose_v(const __hip_bfloat16* __restrict__ qkv, __hip_bfloat16* __restrict__ Vt) {
  __shared__ __hip_bfloat16 tile[32][33];
  const int b = blockIdx.z;
  const __hip_bfloat16* V = qkv + (size_t)b * 2048 * 3072 + 2048;
  __hip_bfloat16* vt = Vt + (size_t)b * 1024 * 2048;
  const int tx = threadIdx.x & 31, ty = threadIdx.x >> 5;  // 32 x 8
  const int m0 = blockIdx.x * 32, d0 = blockIdx.y * 32;
#pragma unroll
  for (int i = 0; i < 32; i += 8)
    tile[ty + i][tx] = V[(size_t)(m0 + ty + i) * 3072 + d0 + tx];
  __syncthreads();
#pragma unroll
  for (int i = 0; i < 32; i += 8)
    vt[(size_t)(d0 + ty + i) * 2048 + m0 + tx] = tile[tx][ty + i];
}

// ---------------- row softmax over 2048 fp32, writes bf16 P in-place ----------------
__global__ __launch_bounds__(256)
void softmax_rows(float* __restrict__ S) {
  float* row = S + (size_t)blockIdx.x * 2048;
  const int t = threadIdx.x, lane = t & 63, wid = t >> 6;
  float4 v0 = ((const float4*)row)[t];
  float4 v1 = ((const float4*)row)[256 + t];
  float vals[8] = {v0.x, v0.y, v0.z, v0.w, v1.x, v1.y, v1.z, v1.w};
  float m = vals[0];
#pragma unroll
  for (int i = 1; i < 8; ++i) m = fmaxf(m, vals[i]);
#pragma unroll
  for (int o = 32; o; o >>= 1) m = fmaxf(m, __shfl_xor(m, o));
  __shared__ float red[4];
  if (lane == 0) red[wid] = m;
  __syncthreads();
  m = fmaxf(fmaxf(red[0], red[1]), fmaxf(red[2], red[3]));
  __syncthreads();
  float p[8], s = 0.f;
#pragma unroll
  for (int i = 0; i < 8; ++i) { p[i] = __expf(vals[i] - m); s += p[i]; }
#pragma unroll
  for (int o = 32; o; o >>= 1) s += __shfl_xor(s, o);
  if (lane == 0) red[wid] = s;
  __syncthreads();
  s = red[0] + red[1] + red[2] + red[3];
  const float inv = 1.0f / s;
  __hip_bfloat16 b[8];
#pragma unroll
  for (int i = 0; i < 8; ++i) b[i] = __float2bfloat16(p[i] * inv);
  ushort4 o0, o1;
  o0.x = *(unsigned short*)&b[0]; o0.y = *(unsigned short*)&b[1];
  o0.z = *(unsigned short*)&b[2]; o0.w = *(unsigned short*)&b[3];
  o1.x = *(unsigned short*)&b[4]; o1.y = *(unsigned short*)&b[5];
  o1.z = *(unsigned short*)&b[6]; o1.w = *(unsigned short*)&b[7];
  unsigned short* prow = (unsigned short*)row;
  ((ushort4*)prow)[t] = o0;
  ((ushort4*)prow)[256 + t] = o1;
}

extern "C" void kernel_launch(void* const* d_in, const int* in_sizes, int n_in,
                              void* d_out, int out_size, void* d_ws, size_t ws_size,
                              hipStream_t stream) {
  const float* x = (const float*)d_in[0];   // [4,2048,1024]
  const float* w = (const float*)d_in[1];   // [3072,1024]
  float* out = (float*)d_out;               // [4,2048,1024] fp32
  char* ws = (char*)d_ws;

  // ws layout (128 MiB):
  //   [0, 67MB)        S fp32 (4 x 2048 x 2048); early-reused for cast buffers
  //   [67MB, 117.4MB)  qkv bf16 [8192 x 3072]
  //   [117.4MB, 128MB) Vt bf16 [4][1024][2048]
  __hip_bfloat16* xb  = (__hip_bfloat16*)ws;
  __hip_bfloat16* wb  = (__hip_bfloat16*)(ws + 16777216);
  float*          S   = (float*)ws;
  __hip_bfloat16* qkv = (__hip_bfloat16*)(ws + 67108864);
  __hip_bfloat16* Vt  = (__hip_bfloat16*)(ws + 117440512);

  cast_f32_bf16<<<1024, 256, 0, stream>>>(x, xb, (4 * 2048 * 1024) / 4);
  cast_f32_bf16<<<512, 256, 0, stream>>>(w, wb, (3072 * 1024) / 4);

  // qkv = x @ w^T   [8192 x 3072], K=1024
  gemm256<__hip_bfloat16><<<dim3(32, 12, 1), 512, 131072, stream>>>(
      xb, 1024, 0L, wb, 1024, 0L, qkv, 3072, 0L, 1024, 1.0f);

  transpose_v<<<dim3(64, 32, 4), 256, 0, stream>>>(qkv, Vt);

  // S_b = (Q_b K_b^T) / 32   [2048 x 2048] x4, K=1024
  gemm256<float><<<dim3(8, 8, 4), 512, 131072, stream>>>(
      qkv, 3072, (long)2048 * 3072, qkv + 1024, 3072, (long)2048 * 3072,
      S, 2048, (long)2048 * 2048, 1024, 0.03125f);

  softmax_rows<<<8192, 256, 0, stream>>>(S);

  // out_b = P_b @ V_b   [2048 x 1024] x4, K=2048
  gemm256<float><<<dim3(8, 4, 4), 512, 131072, stream>>>(
      (const __hip_bfloat16*)S, 4096, (long)2048 * 4096,
      Vt, 2048, (long)1024 * 2048,
      out, 1024, (long)2048 * 1024, 2048, 1.0f);
}

// Round 5
// 260.889 us; speedup vs baseline: 1.1237x; 1.0270x over previous
//
#include <hip/hip_runtime.h>
#include <hip/hip_bf16.h>

// HLiuAttn: out = softmax((x W_qkv^T).q @ .k^T / 32) @ .v
// B=4, N=2048, D=1024. fp32 in/out; bf16 MFMA internally.
// R5: deep-prefetch 8-phase GEMM — ALL stage loads issued at ph0 (tile t+1),
// single vmcnt(0) drain at ph3 after MFMA (~3.5-phase in-flight window).
// GEMM3 uses BM=128 variant (MFRAGS=1) for exact 256-block grid.

typedef __bf16 bf16x8 __attribute__((ext_vector_type(8)));
typedef float f32x4 __attribute__((ext_vector_type(4)));

__device__ __forceinline__ void store_out(float* p, float v) { *p = v; }
__device__ __forceinline__ void store_out(__hip_bfloat16* p, float v) { *p = __float2bfloat16(v); }

#define MFMA16(a, b, c) __builtin_amdgcn_mfma_f32_16x16x32_bf16(a, b, c, 0, 0, 0)

// ---------------- cast fp32 -> bf16 ----------------
__global__ __launch_bounds__(256)
void cast_f32_bf16(const float* __restrict__ in, __hip_bfloat16* __restrict__ out, int n4) {
  for (int i = blockIdx.x * blockDim.x + threadIdx.x; i < n4; i += gridDim.x * blockDim.x) {
    float4 v = ((const float4*)in)[i];
    __hip_bfloat16 b0 = __float2bfloat16(v.x), b1 = __float2bfloat16(v.y),
                   b2 = __float2bfloat16(v.z), b3 = __float2bfloat16(v.w);
    ushort4 o;
    o.x = *(unsigned short*)&b0; o.y = *(unsigned short*)&b1;
    o.z = *(unsigned short*)&b2; o.w = *(unsigned short*)&b3;
    ((ushort4*)out)[i] = o;
  }
}

// ---------------- BM x 256 8-phase GEMM (BM = MFRAGS*128) ----------------
// C[m,n] = sum_k A[m,k] * B^T[n,k].  A [M x K] rm, B^T [N x K] rm.
// LDS buffer: A BMx64 bf16 + B 256x64 bf16, subtiled 1024B, st_16x32 XOR swizzle
// (linear gload_lds dest + inverse-swizzled global source + swizzled ds_read).
//
// Schedule per K-tile t (buf c = t&1):
//   ph0: ds_read A-frags(P0) + ALL B-frags (8) from buf c; issue ALL stage
//        loads for tile t+1 into buf c^1 (legal: buf c^1 reads fully drained
//        by t-1 ph3 lgkmcnt(0) + its final barrier); lgkmcnt(8) hint.
//   ph1,ph2: ds_read A-frags only.
//   each phase: barrier; lgkmcnt(0); sched_barrier; setprio(1); MFMA x8*MFRAGS;
//   setprio(0); [ph3 only: vmcnt(0) — drains t+1 stages, ~3.5 phases in flight]
//   barrier.

#define PHASE(P, CB, PF, K0N)                                                          \
  {                                                                                    \
    bf16x8 af[MFRAGS][2];                                                              \
    _Pragma("unroll") for (int mf = 0; mf < MFRAGS; ++mf) {                            \
      af[mf][0] = frag(CB, 0, wm * (MFRAGS * 64) + (P * MFRAGS + mf) * 16, 0);         \
      af[mf][1] = frag(CB, 0, wm * (MFRAGS * 64) + (P * MFRAGS + mf) * 16, 1);         \
    }                                                                                  \
    if (P == 0) {                                                                      \
      _Pragma("unroll") for (int j = 0; j < 4; ++j) {                                  \
        bfr[j][0] = frag(CB, 1, wn * 64 + j * 16, 0);                                  \
        bfr[j][1] = frag(CB, 1, wn * 64 + j * 16, 1);                                  \
      }                                                                                \
      if (PF) stage_all(CB ^ 1, K0N);                                                  \
      asm volatile("s_waitcnt lgkmcnt(8)" ::: "memory");                               \
    }                                                                                  \
    __builtin_amdgcn_s_barrier();                                                      \
    asm volatile("s_waitcnt lgkmcnt(0)" ::: "memory");                                 \
    __builtin_amdgcn_sched_barrier(0);                                                 \
    __builtin_amdgcn_s_setprio(1);                                                     \
    _Pragma("unroll") for (int j = 0; j < 4; ++j)                                      \
      _Pragma("unroll") for (int mf = 0; mf < MFRAGS; ++mf) {                          \
        acc[P * MFRAGS + mf][j] = MFMA16(af[mf][0], bfr[j][0], acc[P * MFRAGS + mf][j]); \
        acc[P * MFRAGS + mf][j] = MFMA16(af[mf][1], bfr[j][1], acc[P * MFRAGS + mf][j]); \
      }                                                                                \
    __builtin_amdgcn_s_setprio(0);                                                     \
    if (P == 3) asm volatile("s_waitcnt vmcnt(0)" ::: "memory");                       \
    __builtin_amdgcn_s_barrier();                                                      \
  }

template <typename OutT, int MFRAGS>
__global__ __launch_bounds__(512, 2)
void gemm256(const __hip_bfloat16* __restrict__ A, int lda, long sA,
             const __hip_bfloat16* __restrict__ B, int ldb, long sB,
             OutT* __restrict__ C, int ldc, long sC,
             int K, float cscale) {
  constexpr int BM = MFRAGS * 128;
  constexpr int ABYTES = BM * 64 * 2;          // A region per buffer
  constexpr int BUFSZ = ABYTES + 32768;        // + B region (256x64x2)
  extern __shared__ char smem[];               // 2 * BUFSZ
  const int tid = threadIdx.x, lane = tid & 63, wid = tid >> 6;
  const int wm = wid >> 2, wn = wid & 3;       // wave -> (MFRAGS*64) x 64 panel
  A += (long)blockIdx.z * sA; B += (long)blockIdx.z * sB; C += (long)blockIdx.z * sC;
  const long bm = (long)blockIdx.x * BM, bn = (long)blockIdx.y * 256;
  // read-side swizzled lane offset within 1024B subtile
  const int laneOff = (lane & 15) * 64 + (((lane >> 4) * 16) ^ ((lane & 8) ? 32 : 0));
  // stage-side: wave (wid) fills subtile (row0>>4)*2+wid; lane writes lane*16 linear,
  // global source column inverse-swizzled (same involution as read side)
  const int sRowA = (wid >> 1) * 16 + (lane >> 2);
  const int sKs = wid & 1;
  const int sCol = ((lane & 3) * 8) ^ ((lane & 32) ? 16 : 0);
  const int nt = K >> 6;

  auto stage = [&](int cbuf, int reg /*0=A,1=B*/, int row0, int k0) {
    const __hip_bfloat16* g =
        reg ? (B + (bn + row0 + sRowA) * (long)ldb + k0 + sKs * 32 + sCol)
            : (A + (bm + row0 + sRowA) * (long)lda + k0 + sKs * 32 + sCol);
    char* dst = smem + cbuf * BUFSZ + (reg ? ABYTES : 0) + ((row0 >> 4) * 2 + wid) * 1024;
    __builtin_amdgcn_global_load_lds((const __attribute__((address_space(1))) void*)g,
                                     (__attribute__((address_space(3))) void*)dst, 16, 0, 0);
  };
  auto stage_all = [&](int cbuf, int k0) {
    stage(cbuf, 0, 0, k0); stage(cbuf, 0, 64, k0);
    if (MFRAGS == 2) { stage(cbuf, 0, 128, k0); stage(cbuf, 0, 192, k0); }
    stage(cbuf, 1, 0, k0); stage(cbuf, 1, 64, k0);
    stage(cbuf, 1, 128, k0); stage(cbuf, 1, 192, k0);
  };
  auto frag = [&](int cbuf, int reg, int R, int ks) -> bf16x8 {
    return *(const bf16x8*)(smem + cbuf * BUFSZ + (reg ? ABYTES : 0) +
                            ((R >> 4) * 2 + ks) * 1024 + laneOff);
  };

  f32x4 acc[MFRAGS * 4][4] = {};
  bf16x8 bfr[4][2];

  // prologue: tile 0
  stage_all(0, 0);
  asm volatile("s_waitcnt vmcnt(0)" ::: "memory");
  __builtin_amdgcn_s_barrier();

  for (int t = 0; t < nt; t += 2) {
    {
      const int k0n = (t + 1) << 6;  // t+1 < nt always (nt even)
      PHASE(0, 0, true, k0n) PHASE(1, 0, true, k0n)
      PHASE(2, 0, true, k0n) PHASE(3, 0, true, k0n)
    }
    {
      const bool pf = (t + 2) < nt;
      const int k0n = (t + 2) << 6;
      PHASE(0, 1, pf, k0n) PHASE(1, 1, pf, k0n)
      PHASE(2, 1, pf, k0n) PHASE(3, 1, pf, k0n)
    }
  }

  // epilogue: C/D layout col=lane&15, row=(lane>>4)*4+jj [m89-verified]
  const int r0 = (lane >> 4) * 4, cn = lane & 15;
#pragma unroll
  for (int rf = 0; rf < MFRAGS * 4; ++rf)
#pragma unroll
    for (int j = 0; j < 4; ++j) {
      long row = bm + wm * (MFRAGS * 64) + rf * 16 + r0;
      long col = bn + wn * 64 + j * 16 + cn;
#pragma unroll
      for (int jj = 0; jj < 4; ++jj)
        store_out(&C[(row + jj) * (long)ldc + col], acc[rf][j][jj] * cscale);
    }
}

// ---------------- V transpose: Vt[b][d][m] = qkv[b*2048+m][2048+d] ----------------
__global__ __launch_bounds__(256)
void transpose_v(const __hip_bfloat16* __restrict__ qkv, __hip_bfloat16* __restrict__ Vt) {
  __shared__ __hip_bfloat16 tile[32][33];
  const int b = blockIdx.z;
  const __hip_bfloat16* V = qkv + (size_t)b * 2048 * 3072 + 2048;
  __hip_bfloat16* vt = Vt + (size_t)b * 1024 * 2048;
  const int tx = threadIdx.x & 31, ty = threadIdx.x >> 5;  // 32 x 8
  const int m0 = blockIdx.x * 32, d0 = blockIdx.y * 32;
#pragma unroll
  for (int i = 0; i < 32; i += 8)
    tile[ty + i][tx] = V[(size_t)(m0 + ty + i) * 3072 + d0 + tx];
  __syncthreads();
#pragma unroll
  for (int i = 0; i < 32; i += 8)
    vt[(size_t)(d0 + ty + i) * 2048 + m0 + tx] = tile[tx][ty + i];
}

// ---------------- row softmax over 2048 fp32, writes bf16 P in-place ----------------
__global__ __launch_bounds__(256)
void softmax_rows(float* __restrict__ S) {
  float* row = S + (size_t)blockIdx.x * 2048;
  const int t = threadIdx.x, lane = t & 63, wid = t >> 6;
  float4 v0 = ((const float4*)row)[t];
  float4 v1 = ((const float4*)row)[256 + t];
  float vals[8] = {v0.x, v0.y, v0.z, v0.w, v1.x, v1.y, v1.z, v1.w};
  float m = vals[0];
#pragma unroll
  for (int i = 1; i < 8; ++i) m = fmaxf(m, vals[i]);
#pragma unroll
  for (int o = 32; o; o >>= 1) m = fmaxf(m, __shfl_xor(m, o));
  __shared__ float red[4];
  if (lane == 0) red[wid] = m;
  __syncthreads();
  m = fmaxf(fmaxf(red[0], red[1]), fmaxf(red[2], red[3]));
  __syncthreads();
  float p[8], s = 0.f;
#pragma unroll
  for (int i = 0; i < 8; ++i) { p[i] = __expf(vals[i] - m); s += p[i]; }
#pragma unroll
  for (int o = 32; o; o >>= 1) s += __shfl_xor(s, o);
  if (lane == 0) red[wid] = s;
  __syncthreads();
  s = red[0] + red[1] + red[2] + red[3];
  const float inv = 1.0f / s;
  __hip_bfloat16 b[8];
#pragma unroll
  for (int i = 0; i < 8; ++i) b[i] = __float2bfloat16(p[i] * inv);
  ushort4 o0, o1;
  o0.x = *(unsigned short*)&b[0]; o0.y = *(unsigned short*)&b[1];
  o0.z = *(unsigned short*)&b[2]; o0.w = *(unsigned short*)&b[3];
  o1.x = *(unsigned short*)&b[4]; o1.y = *(unsigned short*)&b[5];
  o1.z = *(unsigned short*)&b[6]; o1.w = *(unsigned short*)&b[7];
  unsigned short* prow = (unsigned short*)row;
  ((ushort4*)prow)[t] = o0;
  ((ushort4*)prow)[256 + t] = o1;
}

extern "C" void kernel_launch(void* const* d_in, const int* in_sizes, int n_in,
                              void* d_out, int out_size, void* d_ws, size_t ws_size,
                              hipStream_t stream) {
  const float* x = (const float*)d_in[0];   // [4,2048,1024]
  const float* w = (const float*)d_in[1];   // [3072,1024]
  float* out = (float*)d_out;               // [4,2048,1024] fp32
  char* ws = (char*)d_ws;

  // ws layout (128 MiB):
  //   [0, 67MB)        S fp32 (4 x 2048 x 2048); early-reused for cast buffers
  //   [67MB, 117.4MB)  qkv bf16 [8192 x 3072]
  //   [117.4MB, 128MB) Vt bf16 [4][1024][2048]
  __hip_bfloat16* xb  = (__hip_bfloat16*)ws;
  __hip_bfloat16* wb  = (__hip_bfloat16*)(ws + 16777216);
  float*          S   = (float*)ws;
  __hip_bfloat16* qkv = (__hip_bfloat16*)(ws + 67108864);
  __hip_bfloat16* Vt  = (__hip_bfloat16*)(ws + 117440512);

  cast_f32_bf16<<<1024, 256, 0, stream>>>(x, xb, (4 * 2048 * 1024) / 4);
  cast_f32_bf16<<<512, 256, 0, stream>>>(w, wb, (3072 * 1024) / 4);

  // qkv = x @ w^T   [8192 x 3072], K=1024  (384 blocks — 1.5 rounds, known tail)
  gemm256<__hip_bfloat16, 2><<<dim3(32, 12, 1), 512, 131072, stream>>>(
      xb, 1024, 0L, wb, 1024, 0L, qkv, 3072, 0L, 1024, 1.0f);

  transpose_v<<<dim3(64, 32, 4), 256, 0, stream>>>(qkv, Vt);

  // S_b = (Q_b K_b^T) / 32   [2048 x 2048] x4, K=1024  (256 blocks exact)
  gemm256<float, 2><<<dim3(8, 8, 4), 512, 131072, stream>>>(
      qkv, 3072, (long)2048 * 3072, qkv + 1024, 3072, (long)2048 * 3072,
      S, 2048, (long)2048 * 2048, 1024, 0.03125f);

  softmax_rows<<<8192, 256, 0, stream>>>(S);

  // out_b = P_b @ V_b   [2048 x 1024] x4, K=2048  (BM=128 -> 256 blocks exact)
  gemm256<float, 1><<<dim3(16, 4, 4), 512, 98304, stream>>>(
      (const __hip_bfloat16*)S, 4096, (long)2048 * 4096,
      Vt, 2048, (long)1024 * 2048,
      out, 1024, (long)2048 * 1024, 2048, 1.0f);
}

// Round 8
// 247.090 us; speedup vs baseline: 1.1865x; 1.0558x over previous
//
#include <hip/hip_runtime.h>
#include <hip/hip_bf16.h>

// HLiuAttn: out = softmax((x W_qkv^T).q @ .k^T / 32) @ .v
// B=4, N=2048, D=1024. fp32 in/out; bf16 MFMA internally.
// R6: m201-style continuous pipeline — 2 stage-loads/phase into DEAD regions,
// counted vmcnt(10)/vmcnt(8) (MFRAGS=2) or vmcnt(4) (MFRAGS=1), never 0
// mid-loop. Load in-flight window: 4-6 phases. transpose_v vectorized.

typedef __bf16 bf16x8 __attribute__((ext_vector_type(8)));
typedef float f32x4 __attribute__((ext_vector_type(4)));

__device__ __forceinline__ void store_out(float* p, float v) { *p = v; }
__device__ __forceinline__ void store_out(__hip_bfloat16* p, float v) { *p = __float2bfloat16(v); }

#define MFMA16(a, b, c) __builtin_amdgcn_mfma_f32_16x16x32_bf16(a, b, c, 0, 0, 0)
#define VMW(n) asm volatile("s_waitcnt vmcnt(" #n ")" ::: "memory")
#define NOSTAGE ((void)0)

// ---------------- cast fp32 -> bf16 ----------------
__global__ __launch_bounds__(256)
void cast_f32_bf16(const float* __restrict__ in, __hip_bfloat16* __restrict__ out, int n4) {
  for (int i = blockIdx.x * blockDim.x + threadIdx.x; i < n4; i += gridDim.x * blockDim.x) {
    float4 v = ((const float4*)in)[i];
    __hip_bfloat16 b0 = __float2bfloat16(v.x), b1 = __float2bfloat16(v.y),
                   b2 = __float2bfloat16(v.z), b3 = __float2bfloat16(v.w);
    ushort4 o;
    o.x = *(unsigned short*)&b0; o.y = *(unsigned short*)&b1;
    o.z = *(unsigned short*)&b2; o.w = *(unsigned short*)&b3;
    ((ushort4*)out)[i] = o;
  }
}

// ---------------- BM x 256 pipelined GEMM (BM = MFRAGS*128) ----------------
// C[m,n] = sum_k A[m,k] * B^T[n,k].  A [M x K] rm, B^T [N x K] rm.
// LDS: dbuf x (A BMx64 + B 256x64) bf16, 1024B subtiles, st_16x32 XOR swizzle
// (linear gload_lds dest + inverse-swizzled global source + swizzled ds_read).
//
// Pipeline (MFRAGS=2). Loads for tile T: B01,B23,A02 issued at (T-2)p1/p2/p3;
// A13 at (T-1)p0 — each into a region whose last reader drained lgkmcnt(0)
// before an earlier barrier (race-free). Reads: p0 needs B+A0+A2; p2 needs
// A1+A3 (B frags register-cached at p0; A regions die progressively).
// Counted waits (issue-ledger-derived):
//   p1-end: vmcnt(10) guards this tile's A13   (window 5 phases)
//   p3-end: vmcnt(8)  guards next tile's B+A02 (window 4-6 phases)
// MFRAGS=1: loads {B01,B23 @(T-2)p1/p2, A01 @(T-1)p0}; single p3-end vmcnt(4).
// Tail (last 2 tiles): conservative vmcnt(8)/vmcnt(2)/vmcnt(0).

#define PHASE(P, CB, STAGES, WAITC)                                                    \
  {                                                                                    \
    bf16x8 af[MFRAGS][2];                                                              \
    _Pragma("unroll") for (int mf = 0; mf < MFRAGS; ++mf) {                            \
      af[mf][0] = frag(CB, 0, wm * (MFRAGS * 64) + ((P) * MFRAGS + mf) * 16, 0);       \
      af[mf][1] = frag(CB, 0, wm * (MFRAGS * 64) + ((P) * MFRAGS + mf) * 16, 1);       \
    }                                                                                  \
    if ((P) == 0) {                                                                    \
      _Pragma("unroll") for (int j = 0; j < 4; ++j) {                                  \
        bfr[j][0] = frag(CB, 1, wn * 64 + j * 16, 0);                                  \
        bfr[j][1] = frag(CB, 1, wn * 64 + j * 16, 1);                                  \
      }                                                                                \
    }                                                                                  \
    STAGES;                                                                            \
    __builtin_amdgcn_s_barrier();                                                      \
    asm volatile("s_waitcnt lgkmcnt(0)" ::: "memory");                                 \
    __builtin_amdgcn_sched_barrier(0);                                                 \
    __builtin_amdgcn_s_setprio(1);                                                     \
    _Pragma("unroll") for (int j = 0; j < 4; ++j)                                      \
      _Pragma("unroll") for (int mf = 0; mf < MFRAGS; ++mf) {                          \
        acc[(P) * MFRAGS + mf][j] = MFMA16(af[mf][0], bfr[j][0], acc[(P) * MFRAGS + mf][j]); \
        acc[(P) * MFRAGS + mf][j] = MFMA16(af[mf][1], bfr[j][1], acc[(P) * MFRAGS + mf][j]); \
      }                                                                                \
    __builtin_amdgcn_s_setprio(0);                                                     \
    WAITC;                                                                             \
    __builtin_amdgcn_s_barrier();                                                      \
  }

template <typename OutT, int MFRAGS>
__global__ __launch_bounds__(512, 2)
void gemm256(const __hip_bfloat16* __restrict__ A, int lda, long sA,
             const __hip_bfloat16* __restrict__ B, int ldb, long sB,
             OutT* __restrict__ C, int ldc, long sC,
             int K, float cscale) {
  constexpr int BM = MFRAGS * 128;
  constexpr int ABYTES = BM * 64 * 2;
  constexpr int BUFSZ = ABYTES + 32768;
  extern __shared__ char smem[];
  const int tid = threadIdx.x, lane = tid & 63, wid = tid >> 6;
  const int wm = wid >> 2, wn = wid & 3;
  A += (long)blockIdx.z * sA; B += (long)blockIdx.z * sB; C += (long)blockIdx.z * sC;
  const long bm = (long)blockIdx.x * BM, bn = (long)blockIdx.y * 256;
  const int laneOff = (lane & 15) * 64 + (((lane >> 4) * 16) ^ ((lane & 8) ? 32 : 0));
  const int sRowA = (wid >> 1) * 16 + (lane >> 2);
  const int sKs = wid & 1;
  const int sCol = ((lane & 3) * 8) ^ ((lane & 32) ? 16 : 0);
  const int nt = K >> 6;

  auto stage = [&](int cbuf, int reg /*0=A,1=B*/, int row0, int k0) {
    const __hip_bfloat16* g =
        reg ? (B + (bn + row0 + sRowA) * (long)ldb + k0 + sKs * 32 + sCol)
            : (A + (bm + row0 + sRowA) * (long)lda + k0 + sKs * 32 + sCol);
    char* dst = smem + cbuf * BUFSZ + (reg ? ABYTES : 0) + ((row0 >> 4) * 2 + wid) * 1024;
    __builtin_amdgcn_global_load_lds((const __attribute__((address_space(1))) void*)g,
                                     (__attribute__((address_space(3))) void*)dst, 16, 0, 0);
  };
  auto frag = [&](int cbuf, int reg, int R, int ks) -> bf16x8 {
    return *(const bf16x8*)(smem + cbuf * BUFSZ + (reg ? ABYTES : 0) +
                            ((R >> 4) * 2 + ks) * 1024 + laneOff);
  };

  f32x4 acc[MFRAGS * 4][4] = {};
  bf16x8 bfr[4][2];

  if constexpr (MFRAGS == 2) {
    // prologue: L0 {B, A02, A13}, L1 {B, A02}; guard L0.{B,A02} (younger=8)
    stage(0, 1, 0, 0); stage(0, 1, 64, 0); stage(0, 1, 128, 0); stage(0, 1, 192, 0);
    stage(0, 0, 0, 0); stage(0, 0, 128, 0);
    stage(0, 0, 64, 0); stage(0, 0, 192, 0);
    stage(1, 1, 0, 64); stage(1, 1, 64, 64); stage(1, 1, 128, 64); stage(1, 1, 192, 64);
    stage(1, 0, 0, 64); stage(1, 0, 128, 64);
    VMW(8);
    __builtin_amdgcn_s_barrier();

    for (int t = 0; t < nt - 2; t += 2) {
      const int ka = (t + 1) << 6, kb = (t + 2) << 6;
      PHASE(0, 0, (stage(1, 0, 64, ka), stage(1, 0, 192, ka)), NOSTAGE)   // L(t+1).A13
      PHASE(1, 0, (stage(0, 1, 0, kb), stage(0, 1, 64, kb)), VMW(10))     // L(t+2).B01
      PHASE(2, 0, (stage(0, 1, 128, kb), stage(0, 1, 192, kb)), NOSTAGE)  // L(t+2).B23
      PHASE(3, 0, (stage(0, 0, 0, kb), stage(0, 0, 128, kb)), VMW(8))     // L(t+2).A02
      const int kc = (t + 2) << 6, kd = (t + 3) << 6;
      PHASE(0, 1, (stage(0, 0, 64, kc), stage(0, 0, 192, kc)), NOSTAGE)
      PHASE(1, 1, (stage(1, 1, 0, kd), stage(1, 1, 64, kd)), VMW(10))
      PHASE(2, 1, (stage(1, 1, 128, kd), stage(1, 1, 192, kd)), NOSTAGE)
      PHASE(3, 1, (stage(1, 0, 0, kd), stage(1, 0, 128, kd)), VMW(8))
    }
    // tail: tiles nt-2 (CB0), nt-1 (CB1)
    {
      const int ke = (nt - 1) << 6;
      PHASE(0, 0, (stage(1, 0, 64, ke), stage(1, 0, 192, ke)), NOSTAGE)
      PHASE(1, 0, NOSTAGE, VMW(8))
      PHASE(2, 0, NOSTAGE, NOSTAGE)
      PHASE(3, 0, NOSTAGE, VMW(2))
      PHASE(0, 1, NOSTAGE, NOSTAGE)
      PHASE(1, 1, NOSTAGE, VMW(0))
      PHASE(2, 1, NOSTAGE, NOSTAGE)
      PHASE(3, 1, NOSTAGE, NOSTAGE)
    }
  } else {
    // MFRAGS=1: L(T) = {B01,B23 @(T-2)p1/p2, A01 @(T-1)p0}; p3-end vmcnt(4)
    stage(0, 1, 0, 0); stage(0, 1, 64, 0); stage(0, 1, 128, 0); stage(0, 1, 192, 0);
    stage(0, 0, 0, 0); stage(0, 0, 64, 0);
    stage(1, 1, 0, 64); stage(1, 1, 64, 64); stage(1, 1, 128, 64); stage(1, 1, 192, 64);
    VMW(4);
    __builtin_amdgcn_s_barrier();

    for (int t = 0; t < nt - 2; t += 2) {
      const int ka = (t + 1) << 6, kb = (t + 2) << 6;
      PHASE(0, 0, (stage(1, 0, 0, ka), stage(1, 0, 64, ka)), NOSTAGE)     // L(t+1).A01
      PHASE(1, 0, (stage(0, 1, 0, kb), stage(0, 1, 64, kb)), NOSTAGE)
      PHASE(2, 0, (stage(0, 1, 128, kb), stage(0, 1, 192, kb)), NOSTAGE)
      PHASE(3, 0, NOSTAGE, VMW(4))
      const int kc = (t + 2) << 6, kd = (t + 3) << 6;
      PHASE(0, 1, (stage(0, 0, 0, kc), stage(0, 0, 64, kc)), NOSTAGE)
      PHASE(1, 1, (stage(1, 1, 0, kd), stage(1, 1, 64, kd)), NOSTAGE)
      PHASE(2, 1, (stage(1, 1, 128, kd), stage(1, 1, 192, kd)), NOSTAGE)
      PHASE(3, 1, NOSTAGE, VMW(4))
    }
    {
      const int ke = (nt - 1) << 6;
      PHASE(0, 0, (stage(1, 0, 0, ke), stage(1, 0, 64, ke)), NOSTAGE)
      PHASE(1, 0, NOSTAGE, NOSTAGE)
      PHASE(2, 0, NOSTAGE, NOSTAGE)
      PHASE(3, 0, NOSTAGE, VMW(0))
      PHASE(0, 1, NOSTAGE, NOSTAGE)
      PHASE(1, 1, NOSTAGE, NOSTAGE)
      PHASE(2, 1, NOSTAGE, NOSTAGE)
      PHASE(3, 1, NOSTAGE, NOSTAGE)
    }
  }

  // epilogue: C/D layout col=lane&15, row=(lane>>4)*4+jj [m89-verified]
  const int r0 = (lane >> 4) * 4, cn = lane & 15;
#pragma unroll
  for (int rf = 0; rf < MFRAGS * 4; ++rf)
#pragma unroll
    for (int j = 0; j < 4; ++j) {
      long row = bm + wm * (MFRAGS * 64) + rf * 16 + r0;
      long col = bn + wn * 64 + j * 16 + cn;
#pragma unroll
      for (int jj = 0; jj < 4; ++jj)
        store_out(&C[(row + jj) * (long)ldc + col], acc[rf][j][jj] * cscale);
    }
}

// ---------------- V transpose (vectorized): Vt[b][d][m] = qkv[b*2048+m][2048+d] ----------------
__global__ __launch_bounds__(256)
void transpose_v(const __hip_bfloat16* __restrict__ qkv, __hip_bfloat16* __restrict__ Vt) {
  __shared__ unsigned short tr[64][68];
  const int b = blockIdx.z;
  const unsigned short* V = (const unsigned short*)(qkv + (size_t)b * 2048 * 3072 + 2048);
  unsigned short* vt = (unsigned short*)(Vt + (size_t)b * 1024 * 2048);
  const int m0 = blockIdx.x * 64, d0 = blockIdx.y * 64;
  const int t = threadIdx.x;
#pragma unroll
  for (int i = 0; i < 4; ++i) {
    int idx = i * 256 + t;
    int m = idx >> 4, dc = (idx & 15) * 4;
    ushort4 v = *(const ushort4*)&V[(size_t)(m0 + m) * 3072 + d0 + dc];
    tr[dc + 0][m] = v.x; tr[dc + 1][m] = v.y; tr[dc + 2][m] = v.z; tr[dc + 3][m] = v.w;
  }
  __syncthreads();
#pragma unroll
  for (int i = 0; i < 4; ++i) {
    int idx = i * 256 + t;
    int d = idx >> 4, mc = (idx & 15) * 4;
    ushort4 o;
    o.x = tr[d][mc]; o.y = tr[d][mc + 1]; o.z = tr[d][mc + 2]; o.w = tr[d][mc + 3];
    *(ushort4*)&vt[(size_t)(d0 + d) * 2048 + m0 + mc] = o;
  }
}

// ---------------- row softmax over 2048 fp32, writes bf16 P in-place ----------------
__global__ __launch_bounds__(256)
void softmax_rows(float* __restrict__ S) {
  float* row = S + (size_t)blockIdx.x * 2048;
  const int t = threadIdx.x, lane = t & 63, wid = t >> 6;
  float4 v0 = ((const float4*)row)[t];
  float4 v1 = ((const float4*)row)[256 + t];
  float vals[8] = {v0.x, v0.y, v0.z, v0.w, v1.x, v1.y, v1.z, v1.w};
  float m = vals[0];
#pragma unroll
  for (int i = 1; i < 8; ++i) m = fmaxf(m, vals[i]);
#pragma unroll
  for (int o = 32; o; o >>= 1) m = fmaxf(m, __shfl_xor(m, o));
  __shared__ float red[4];
  if (lane == 0) red[wid] = m;
  __syncthreads();
  m = fmaxf(fmaxf(red[0], red[1]), fmaxf(red[2], red[3]));
  __syncthreads();
  float p[8], s = 0.f;
#pragma unroll
  for (int i = 0; i < 8; ++i) { p[i] = __expf(vals[i] - m); s += p[i]; }
#pragma unroll
  for (int o = 32; o; o >>= 1) s += __shfl_xor(s, o);
  if (lane == 0) red[wid] = s;
  __syncthreads();
  s = red[0] + red[1] + red[2] + red[3];
  const float inv = 1.0f / s;
  __hip_bfloat16 b[8];
#pragma unroll
  for (int i = 0; i < 8; ++i) b[i] = __float2bfloat16(p[i] * inv);
  ushort4 o0, o1;
  o0.x = *(unsigned short*)&b[0]; o0.y = *(unsigned short*)&b[1];
  o0.z = *(unsigned short*)&b[2]; o0.w = *(unsigned short*)&b[3];
  o1.x = *(unsigned short*)&b[4]; o1.y = *(unsigned short*)&b[5];
  o1.z = *(unsigned short*)&b[6]; o1.w = *(unsigned short*)&b[7];
  unsigned short* prow = (unsigned short*)row;
  ((ushort4*)prow)[t] = o0;
  ((ushort4*)prow)[256 + t] = o1;
}

extern "C" void kernel_launch(void* const* d_in, const int* in_sizes, int n_in,
                              void* d_out, int out_size, void* d_ws, size_t ws_size,
                              hipStream_t stream) {
  const float* x = (const float*)d_in[0];   // [4,2048,1024]
  const float* w = (const float*)d_in[1];   // [3072,1024]
  float* out = (float*)d_out;               // [4,2048,1024] fp32
  char* ws = (char*)d_ws;

  __hip_bfloat16* xb  = (__hip_bfloat16*)ws;
  __hip_bfloat16* wb  = (__hip_bfloat16*)(ws + 16777216);
  float*          S   = (float*)ws;
  __hip_bfloat16* qkv = (__hip_bfloat16*)(ws + 67108864);
  __hip_bfloat16* Vt  = (__hip_bfloat16*)(ws + 117440512);

  cast_f32_bf16<<<1024, 256, 0, stream>>>(x, xb, (4 * 2048 * 1024) / 4);
  cast_f32_bf16<<<512, 256, 0, stream>>>(w, wb, (3072 * 1024) / 4);

  // qkv = x @ w^T   [8192 x 3072], K=1024
  gemm256<__hip_bfloat16, 2><<<dim3(32, 12, 1), 512, 131072, stream>>>(
      xb, 1024, 0L, wb, 1024, 0L, qkv, 3072, 0L, 1024, 1.0f);

  transpose_v<<<dim3(32, 16, 4), 256, 0, stream>>>(qkv, Vt);

  // S_b = (Q_b K_b^T) / 32   [2048 x 2048] x4, K=1024
  gemm256<float, 2><<<dim3(8, 8, 4), 512, 131072, stream>>>(
      qkv, 3072, (long)2048 * 3072, qkv + 1024, 3072, (long)2048 * 3072,
      S, 2048, (long)2048 * 2048, 1024, 0.03125f);

  softmax_rows<<<8192, 256, 0, stream>>>(S);

  // out_b = P_b @ V_b   [2048 x 1024] x4, K=2048
  gemm256<float, 1><<<dim3(16, 4, 4), 512, 98304, stream>>>(
      (const __hip_bfloat16*)S, 4096, (long)2048 * 4096,
      Vt, 2048, (long)1024 * 2048,
      out, 1024, (long)2048 * 1024, 2048, 1.0f);
}

// Round 9
// 242.456 us; speedup vs baseline: 1.2092x; 1.0191x over previous
//
#include <hip/hip_runtime.h>
#include <hip/hip_bf16.h>

// HLiuAttn: out = softmax((x W_qkv^T).q @ .k^T / 32) @ .v
// B=4, N=2048, D=1024. fp32 in/out; bf16 MFMA internally.
// R9: R6 pipeline MINUS sched_barrier(0) in PHASE (m141: order-pinning cost
// −42%; compiler tracks frag-load->MFMA deps itself, so it's safe to let it
// hoist next-phase addr VALU into the MFMA cluster).

typedef __bf16 bf16x8 __attribute__((ext_vector_type(8)));
typedef float f32x4 __attribute__((ext_vector_type(4)));

__device__ __forceinline__ void store_out(float* p, float v) { *p = v; }
__device__ __forceinline__ void store_out(__hip_bfloat16* p, float v) { *p = __float2bfloat16(v); }

#define MFMA16(a, b, c) __builtin_amdgcn_mfma_f32_16x16x32_bf16(a, b, c, 0, 0, 0)
#define VMW(n) asm volatile("s_waitcnt vmcnt(" #n ")" ::: "memory")
#define NOSTAGE ((void)0)

// ---------------- cast fp32 -> bf16 ----------------
__global__ __launch_bounds__(256)
void cast_f32_bf16(const float* __restrict__ in, __hip_bfloat16* __restrict__ out, int n4) {
  for (int i = blockIdx.x * blockDim.x + threadIdx.x; i < n4; i += gridDim.x * blockDim.x) {
    float4 v = ((const float4*)in)[i];
    __hip_bfloat16 b0 = __float2bfloat16(v.x), b1 = __float2bfloat16(v.y),
                   b2 = __float2bfloat16(v.z), b3 = __float2bfloat16(v.w);
    ushort4 o;
    o.x = *(unsigned short*)&b0; o.y = *(unsigned short*)&b1;
    o.z = *(unsigned short*)&b2; o.w = *(unsigned short*)&b3;
    ((ushort4*)out)[i] = o;
  }
}

// ---------------- BM x 256 pipelined GEMM (BM = MFRAGS*128) ----------------
// C[m,n] = sum_k A[m,k] * B^T[n,k].  A [M x K] rm, B^T [N x K] rm.
// LDS: dbuf x (A BMx64 + B 256x64) bf16, 1024B subtiles, st_16x32 XOR swizzle
// (linear gload_lds dest + inverse-swizzled global source + swizzled ds_read).
//
// Pipeline (MFRAGS=2). Loads for tile T: B01,B23,A02 issued at (T-2)p1/p2/p3;
// A13 at (T-1)p0 — each into a region whose last reader drained lgkmcnt(0)
// before an earlier barrier (race-free).
// Counted waits: p1-end vmcnt(10) guards this tile's A13 (window 5 phases);
// p3-end vmcnt(8) guards next tile's B+A02 (window 4-6 phases).
// MFRAGS=1: loads {B01,B23 @(T-2)p1/p2, A01 @(T-1)p0}; single p3-end vmcnt(4).
// NO sched_barrier(0): compiler may interleave next-phase addr/issue with MFMA.

#define PHASE(P, CB, STAGES, WAITC)                                                    \
  {                                                                                    \
    bf16x8 af[MFRAGS][2];                                                              \
    _Pragma("unroll") for (int mf = 0; mf < MFRAGS; ++mf) {                            \
      af[mf][0] = frag(CB, 0, wm * (MFRAGS * 64) + ((P) * MFRAGS + mf) * 16, 0);       \
      af[mf][1] = frag(CB, 0, wm * (MFRAGS * 64) + ((P) * MFRAGS + mf) * 16, 1);       \
    }                                                                                  \
    if ((P) == 0) {                                                                    \
      _Pragma("unroll") for (int j = 0; j < 4; ++j) {                                  \
        bfr[j][0] = frag(CB, 1, wn * 64 + j * 16, 0);                                  \
        bfr[j][1] = frag(CB, 1, wn * 64 + j * 16, 1);                                  \
      }                                                                                \
    }                                                                                  \
    STAGES;                                                                            \
    __builtin_amdgcn_s_barrier();                                                      \
    asm volatile("s_waitcnt lgkmcnt(0)" ::: "memory");                                 \
    __builtin_amdgcn_s_setprio(1);                                                     \
    _Pragma("unroll") for (int j = 0; j < 4; ++j)                                      \
      _Pragma("unroll") for (int mf = 0; mf < MFRAGS; ++mf) {                          \
        acc[(P) * MFRAGS + mf][j] = MFMA16(af[mf][0], bfr[j][0], acc[(P) * MFRAGS + mf][j]); \
        acc[(P) * MFRAGS + mf][j] = MFMA16(af[mf][1], bfr[j][1], acc[(P) * MFRAGS + mf][j]); \
      }                                                                                \
    __builtin_amdgcn_s_setprio(0);                                                     \
    WAITC;                                                                             \
    __builtin_amdgcn_s_barrier();                                                      \
  }

template <typename OutT, int MFRAGS>
__global__ __launch_bounds__(512, 2)
void gemm256(const __hip_bfloat16* __restrict__ A, int lda, long sA,
             const __hip_bfloat16* __restrict__ B, int ldb, long sB,
             OutT* __restrict__ C, int ldc, long sC,
             int K, float cscale) {
  constexpr int BM = MFRAGS * 128;
  constexpr int ABYTES = BM * 64 * 2;
  constexpr int BUFSZ = ABYTES + 32768;
  extern __shared__ char smem[];
  const int tid = threadIdx.x, lane = tid & 63, wid = tid >> 6;
  const int wm = wid >> 2, wn = wid & 3;
  A += (long)blockIdx.z * sA; B += (long)blockIdx.z * sB; C += (long)blockIdx.z * sC;
  const long bm = (long)blockIdx.x * BM, bn = (long)blockIdx.y * 256;
  const int laneOff = (lane & 15) * 64 + (((lane >> 4) * 16) ^ ((lane & 8) ? 32 : 0));
  const int sRowA = (wid >> 1) * 16 + (lane >> 2);
  const int sKs = wid & 1;
  const int sCol = ((lane & 3) * 8) ^ ((lane & 32) ? 16 : 0);
  const int nt = K >> 6;

  auto stage = [&](int cbuf, int reg /*0=A,1=B*/, int row0, int k0) {
    const __hip_bfloat16* g =
        reg ? (B + (bn + row0 + sRowA) * (long)ldb + k0 + sKs * 32 + sCol)
            : (A + (bm + row0 + sRowA) * (long)lda + k0 + sKs * 32 + sCol);
    char* dst = smem + cbuf * BUFSZ + (reg ? ABYTES : 0) + ((row0 >> 4) * 2 + wid) * 1024;
    __builtin_amdgcn_global_load_lds((const __attribute__((address_space(1))) void*)g,
                                     (__attribute__((address_space(3))) void*)dst, 16, 0, 0);
  };
  auto frag = [&](int cbuf, int reg, int R, int ks) -> bf16x8 {
    return *(const bf16x8*)(smem + cbuf * BUFSZ + (reg ? ABYTES : 0) +
                            ((R >> 4) * 2 + ks) * 1024 + laneOff);
  };

  f32x4 acc[MFRAGS * 4][4] = {};
  bf16x8 bfr[4][2];

  if constexpr (MFRAGS == 2) {
    // prologue: L0 {B, A02, A13}, L1 {B, A02}; guard L0.{B,A02} (younger=8)
    stage(0, 1, 0, 0); stage(0, 1, 64, 0); stage(0, 1, 128, 0); stage(0, 1, 192, 0);
    stage(0, 0, 0, 0); stage(0, 0, 128, 0);
    stage(0, 0, 64, 0); stage(0, 0, 192, 0);
    stage(1, 1, 0, 64); stage(1, 1, 64, 64); stage(1, 1, 128, 64); stage(1, 1, 192, 64);
    stage(1, 0, 0, 64); stage(1, 0, 128, 64);
    VMW(8);
    __builtin_amdgcn_s_barrier();

    for (int t = 0; t < nt - 2; t += 2) {
      const int ka = (t + 1) << 6, kb = (t + 2) << 6;
      PHASE(0, 0, (stage(1, 0, 64, ka), stage(1, 0, 192, ka)), NOSTAGE)   // L(t+1).A13
      PHASE(1, 0, (stage(0, 1, 0, kb), stage(0, 1, 64, kb)), VMW(10))     // L(t+2).B01
      PHASE(2, 0, (stage(0, 1, 128, kb), stage(0, 1, 192, kb)), NOSTAGE)  // L(t+2).B23
      PHASE(3, 0, (stage(0, 0, 0, kb), stage(0, 0, 128, kb)), VMW(8))     // L(t+2).A02
      const int kc = (t + 2) << 6, kd = (t + 3) << 6;
      PHASE(0, 1, (stage(0, 0, 64, kc), stage(0, 0, 192, kc)), NOSTAGE)
      PHASE(1, 1, (stage(1, 1, 0, kd), stage(1, 1, 64, kd)), VMW(10))
      PHASE(2, 1, (stage(1, 1, 128, kd), stage(1, 1, 192, kd)), NOSTAGE)
      PHASE(3, 1, (stage(1, 0, 0, kd), stage(1, 0, 128, kd)), VMW(8))
    }
    // tail: tiles nt-2 (CB0), nt-1 (CB1)
    {
      const int ke = (nt - 1) << 6;
      PHASE(0, 0, (stage(1, 0, 64, ke), stage(1, 0, 192, ke)), NOSTAGE)
      PHASE(1, 0, NOSTAGE, VMW(8))
      PHASE(2, 0, NOSTAGE, NOSTAGE)
      PHASE(3, 0, NOSTAGE, VMW(2))
      PHASE(0, 1, NOSTAGE, NOSTAGE)
      PHASE(1, 1, NOSTAGE, VMW(0))
      PHASE(2, 1, NOSTAGE, NOSTAGE)
      PHASE(3, 1, NOSTAGE, NOSTAGE)
    }
  } else {
    // MFRAGS=1: L(T) = {B01,B23 @(T-2)p1/p2, A01 @(T-1)p0}; p3-end vmcnt(4)
    stage(0, 1, 0, 0); stage(0, 1, 64, 0); stage(0, 1, 128, 0); stage(0, 1, 192, 0);
    stage(0, 0, 0, 0); stage(0, 0, 64, 0);
    stage(1, 1, 0, 64); stage(1, 1, 64, 64); stage(1, 1, 128, 64); stage(1, 1, 192, 64);
    VMW(4);
    __builtin_amdgcn_s_barrier();

    for (int t = 0; t < nt - 2; t += 2) {
      const int ka = (t + 1) << 6, kb = (t + 2) << 6;
      PHASE(0, 0, (stage(1, 0, 0, ka), stage(1, 0, 64, ka)), NOSTAGE)     // L(t+1).A01
      PHASE(1, 0, (stage(0, 1, 0, kb), stage(0, 1, 64, kb)), NOSTAGE)
      PHASE(2, 0, (stage(0, 1, 128, kb), stage(0, 1, 192, kb)), NOSTAGE)
      PHASE(3, 0, NOSTAGE, VMW(4))
      const int kc = (t + 2) << 6, kd = (t + 3) << 6;
      PHASE(0, 1, (stage(0, 0, 0, kc), stage(0, 0, 64, kc)), NOSTAGE)
      PHASE(1, 1, (stage(1, 1, 0, kd), stage(1, 1, 64, kd)), NOSTAGE)
      PHASE(2, 1, (stage(1, 1, 128, kd), stage(1, 1, 192, kd)), NOSTAGE)
      PHASE(3, 1, NOSTAGE, VMW(4))
    }
    {
      const int ke = (nt - 1) << 6;
      PHASE(0, 0, (stage(1, 0, 0, ke), stage(1, 0, 64, ke)), NOSTAGE)
      PHASE(1, 0, NOSTAGE, NOSTAGE)
      PHASE(2, 0, NOSTAGE, NOSTAGE)
      PHASE(3, 0, NOSTAGE, VMW(0))
      PHASE(0, 1, NOSTAGE, NOSTAGE)
      PHASE(1, 1, NOSTAGE, NOSTAGE)
      PHASE(2, 1, NOSTAGE, NOSTAGE)
      PHASE(3, 1, NOSTAGE, NOSTAGE)
    }
  }

  // epilogue: C/D layout col=lane&15, row=(lane>>4)*4+jj [m89-verified]
  const int r0 = (lane >> 4) * 4, cn = lane & 15;
#pragma unroll
  for (int rf = 0; rf < MFRAGS * 4; ++rf)
#pragma unroll
    for (int j = 0; j < 4; ++j) {
      long row = bm + wm * (MFRAGS * 64) + rf * 16 + r0;
      long col = bn + wn * 64 + j * 16 + cn;
#pragma unroll
      for (int jj = 0; jj < 4; ++jj)
        store_out(&C[(row + jj) * (long)ldc + col], acc[rf][j][jj] * cscale);
    }
}

// ---------------- V transpose (vectorized): Vt[b][d][m] = qkv[b*2048+m][2048+d] ----------------
__global__ __launch_bounds__(256)
void transpose_v(const __hip_bfloat16* __restrict__ qkv, __hip_bfloat16* __restrict__ Vt) {
  __shared__ unsigned short tr[64][68];
  const int b = blockIdx.z;
  const unsigned short* V = (const unsigned short*)(qkv + (size_t)b * 2048 * 3072 + 2048);
  unsigned short* vt = (unsigned short*)(Vt + (size_t)b * 1024 * 2048);
  const int m0 = blockIdx.x * 64, d0 = blockIdx.y * 64;
  const int t = threadIdx.x;
#pragma unroll
  for (int i = 0; i < 4; ++i) {
    int idx = i * 256 + t;
    int m = idx >> 4, dc = (idx & 15) * 4;
    ushort4 v = *(const ushort4*)&V[(size_t)(m0 + m) * 3072 + d0 + dc];
    tr[dc + 0][m] = v.x; tr[dc + 1][m] = v.y; tr[dc + 2][m] = v.z; tr[dc + 3][m] = v.w;
  }
  __syncthreads();
#pragma unroll
  for (int i = 0; i < 4; ++i) {
    int idx = i * 256 + t;
    int d = idx >> 4, mc = (idx & 15) * 4;
    ushort4 o;
    o.x = tr[d][mc]; o.y = tr[d][mc + 1]; o.z = tr[d][mc + 2]; o.w = tr[d][mc + 3];
    *(ushort4*)&vt[(size_t)(d0 + d) * 2048 + m0 + mc] = o;
  }
}

// ---------------- row softmax over 2048 fp32, writes bf16 P in-place ----------------
__global__ __launch_bounds__(256)
void softmax_rows(float* __restrict__ S) {
  float* row = S + (size_t)blockIdx.x * 2048;
  const int t = threadIdx.x, lane = t & 63, wid = t >> 6;
  float4 v0 = ((const float4*)row)[t];
  float4 v1 = ((const float4*)row)[256 + t];
  float vals[8] = {v0.x, v0.y, v0.z, v0.w, v1.x, v1.y, v1.z, v1.w};
  float m = vals[0];
#pragma unroll
  for (int i = 1; i < 8; ++i) m = fmaxf(m, vals[i]);
#pragma unroll
  for (int o = 32; o; o >>= 1) m = fmaxf(m, __shfl_xor(m, o));
  __shared__ float red[4];
  if (lane == 0) red[wid] = m;
  __syncthreads();
  m = fmaxf(fmaxf(red[0], red[1]), fmaxf(red[2], red[3]));
  __syncthreads();
  float p[8], s = 0.f;
#pragma unroll
  for (int i = 0; i < 8; ++i) { p[i] = __expf(vals[i] - m); s += p[i]; }
#pragma unroll
  for (int o = 32; o; o >>= 1) s += __shfl_xor(s, o);
  if (lane == 0) red[wid] = s;
  __syncthreads();
  s = red[0] + red[1] + red[2] + red[3];
  const float inv = 1.0f / s;
  __hip_bfloat16 b[8];
#pragma unroll
  for (int i = 0; i < 8; ++i) b[i] = __float2bfloat16(p[i] * inv);
  ushort4 o0, o1;
  o0.x = *(unsigned short*)&b[0]; o0.y = *(unsigned short*)&b[1];
  o0.z = *(unsigned short*)&b[2]; o0.w = *(unsigned short*)&b[3];
  o1.x = *(unsigned short*)&b[4]; o1.y = *(unsigned short*)&b[5];
  o1.z = *(unsigned short*)&b[6]; o1.w = *(unsigned short*)&b[7];
  unsigned short* prow = (unsigned short*)row;
  ((ushort4*)prow)[t] = o0;
  ((ushort4*)prow)[256 + t] = o1;
}

extern "C" void kernel_launch(void* const* d_in, const int* in_sizes, int n_in,
                              void* d_out, int out_size, void* d_ws, size_t ws_size,
                              hipStream_t stream) {
  const float* x = (const float*)d_in[0];   // [4,2048,1024]
  const float* w = (const float*)d_in[1];   // [3072,1024]
  float* out = (float*)d_out;               // [4,2048,1024] fp32
  char* ws = (char*)d_ws;

  __hip_bfloat16* xb  = (__hip_bfloat16*)ws;
  __hip_bfloat16* wb  = (__hip_bfloat16*)(ws + 16777216);
  float*          S   = (float*)ws;
  __hip_bfloat16* qkv = (__hip_bfloat16*)(ws + 67108864);
  __hip_bfloat16* Vt  = (__hip_bfloat16*)(ws + 117440512);

  cast_f32_bf16<<<1024, 256, 0, stream>>>(x, xb, (4 * 2048 * 1024) / 4);
  cast_f32_bf16<<<512, 256, 0, stream>>>(w, wb, (3072 * 1024) / 4);

  // qkv = x @ w^T   [8192 x 3072], K=1024
  gemm256<__hip_bfloat16, 2><<<dim3(32, 12, 1), 512, 131072, stream>>>(
      xb, 1024, 0L, wb, 1024, 0L, qkv, 3072, 0L, 1024, 1.0f);

  transpose_v<<<dim3(32, 16, 4), 256, 0, stream>>>(qkv, Vt);

  // S_b = (Q_b K_b^T) / 32   [2048 x 2048] x4, K=1024
  gemm256<float, 2><<<dim3(8, 8, 4), 512, 131072, stream>>>(
      qkv, 3072, (long)2048 * 3072, qkv + 1024, 3072, (long)2048 * 3072,
      S, 2048, (long)2048 * 2048, 1024, 0.03125f);

  softmax_rows<<<8192, 256, 0, stream>>>(S);

  // out_b = P_b @ V_b   [2048 x 1024] x4, K=2048
  gemm256<float, 1><<<dim3(16, 4, 4), 512, 98304, stream>>>(
      (const __hip_bfloat16*)S, 4096, (long)2048 * 4096,
      Vt, 2048, (long)1024 * 2048,
      out, 1024, (long)2048 * 1024, 2048, 1.0f);
}